// Round 9
// baseline (249.257 us; speedup 1.0000x reference)
//
#include <hip/hip_runtime.h>

typedef float f32x4 __attribute__((ext_vector_type(4)));
typedef short bf16x8 __attribute__((ext_vector_type(8)));

#define NTOK 8192
#define DIM  1024
#define NE   8
#define NH   512
#define NO   1024

static __device__ __forceinline__ unsigned short f2bf(float f) {
  unsigned u = __float_as_uint(f);
  u += 0x7fffu + ((u >> 16) & 1u);
  return (unsigned short)(u >> 16);
}
static __device__ __forceinline__ unsigned pk2(float a, float b) {
  return (unsigned)f2bf(a) | ((unsigned)f2bf(b) << 16);
}

static __device__ __forceinline__ f32x4 mfma_bf16(bf16x8 a, bf16x8 b, f32x4 c) {
  return __builtin_amdgcn_mfma_f32_16x16x32_bf16(a, b, c, 0, 0, 0);
}

// ---------------------------------------------------------------------------
// Gate: fp64 logits -> top-4 bitmask byte per token. Also zeroes d_out
// (16 floats/thread) so moe_ffn can atomicAdd partials.
// ---------------------------------------------------------------------------
__global__ __launch_bounds__(256) void gate_kernel(
    const float* __restrict__ x, const float* __restrict__ wg,
    unsigned char* __restrict__ msk8, float* __restrict__ out)
{
  {
    size_t t = (size_t)blockIdx.x * 256 + threadIdx.x;
    float4* op = (float4*)(out + t * 16);
    float4 z4 = {0.f, 0.f, 0.f, 0.f};
    op[0] = z4; op[1] = z4; op[2] = z4; op[3] = z4;
  }
  const int lane = threadIdx.x & 63;
  const int wv = threadIdx.x >> 6;
  const int n = blockIdx.x * 4 + wv;
  const float* xr = x + (size_t)n * DIM;
  float4 v[4];
#pragma unroll
  for (int i = 0; i < 4; ++i) v[i] = *(const float4*)(xr + i * 256 + lane * 4);
  double logit[NE];
#pragma unroll
  for (int e = 0; e < NE; ++e) {
    const float* wr = wg + e * DIM;
    double s = 0.0;
#pragma unroll
    for (int i = 0; i < 4; ++i) {
      float4 g = *(const float4*)(wr + i * 256 + lane * 4);
      s += (double)v[i].x * g.x + (double)v[i].y * g.y +
           (double)v[i].z * g.z + (double)v[i].w * g.w;
    }
#pragma unroll
    for (int off = 32; off; off >>= 1) s += __shfl_down(s, off);
    logit[e] = s;
  }
  if (lane == 0) {
    unsigned sel = 0;
#pragma unroll
    for (int t = 0; t < 4; ++t) {
      int best = 0; double bv = -1.0e300;
#pragma unroll
      for (int e = 0; e < NE; ++e)
        if (!((sel >> e) & 1) && logit[e] > bv) { bv = logit[e]; best = e; }
      sel |= 1u << best;
    }
    msk8[n] = (unsigned char)sel;
  }
}

// ---------------------------------------------------------------------------
// Weight packs (unchanged): fragment-major bf16.
// w1p [e][nt:32][ks:32][lane:64][j:8]; elem = w1[e][nt*16+(l&15)][ks*32+(l>>4)*8+j]
// w2p [e][ot:64][ks2:16][lane:64][j:8]; elem = w2[e][ot*16+(l&15)][ks2*32+(l>>4)*8+j]
// ---------------------------------------------------------------------------
__global__ __launch_bounds__(256) void pack_w1_kernel(
    const float* __restrict__ w1, unsigned short* __restrict__ w1p)
{
  int t = blockIdx.x * 256 + threadIdx.x;
  int lane = t & 63, ks = (t >> 6) & 31, nt = (t >> 11) & 31, e = t >> 16;
  int r = nt * 16 + (lane & 15);
  int c = ks * 32 + (lane >> 4) * 8;
  const float* src = w1 + ((size_t)(e * 512 + r)) * 1024 + c;
  float4 f0 = *(const float4*)src;
  float4 f1 = *(const float4*)(src + 4);
  uint4 v;
  v.x = pk2(f0.x, f0.y); v.y = pk2(f0.z, f0.w);
  v.z = pk2(f1.x, f1.y); v.w = pk2(f1.z, f1.w);
  *(uint4*)(w1p + (size_t)t * 8) = v;
}

__global__ __launch_bounds__(256) void pack_w2_kernel(
    const float* __restrict__ w2, unsigned short* __restrict__ w2p)
{
  int t = blockIdx.x * 256 + threadIdx.x;
  int lane = t & 63, ks = (t >> 6) & 15, ot = (t >> 10) & 63, e = t >> 16;
  int o = ot * 16 + (lane & 15);
  int h = ks * 32 + (lane >> 4) * 8;
  const float* src = w2 + ((size_t)(e * 1024 + o)) * 512 + h;
  float4 f0 = *(const float4*)src;
  float4 f1 = *(const float4*)(src + 4);
  uint4 v;
  v.x = pk2(f0.x, f0.y); v.y = pk2(f0.z, f0.w);
  v.z = pk2(f1.x, f1.y); v.w = pk2(f1.z, f1.w);
  *(uint4*)(w2p + (size_t)t * 8) = v;
}

// ---------------------------------------------------------------------------
// Fused MoE FFN, round 9: 8 waves (512 thr), BM=64, expert-split, ILP-deep.
//   GEMM1 pass hh: wave owns n-frags {wv+16hh, wv+8+16hh}  (F=2, B unique)
//   GEMM2 chunk hh: wave owns O-frags wv*8..wv*8+7         (F=8, B unique)
//   per expert: [G1p0 | bar epi0 bar | G2c0 ; G1p1 | bar epi1 bar | G2c1]
// LDS: xs 128 KB + hs 32 KB = 160 KB. Budgets: MFMA 66us, VMEM 58, LDS 51.
// XCD swizzle: blocks with same expert-quad land on same 4 XCDs (hot L2).
// Partials (2/element) via atomicAdd; out zeroed by gate.
// ---------------------------------------------------------------------------
__global__ __launch_bounds__(512, 2) void moe_ffn(
    const float* __restrict__ x, const unsigned short* __restrict__ w1p,
    const unsigned short* __restrict__ w2p, const unsigned char* __restrict__ msk8,
    float* __restrict__ out)
{
  __shared__ unsigned short xs[128 * 64 * 8];  // 128 KB: frag f = ks*4+m
  __shared__ unsigned short hs[32 * 64 * 8];   // 32 KB: frag fr = ks2*4+m

  const int tid = threadIdx.x;
  const int lane = tid & 63;
  const int wv = tid >> 6;                     // 0..7
  // XCD-aware swizzle: bid = eq*4 + (tg&3) + 8*(tg>>2)  (bijective on 256)
  const int bid = blockIdx.x;
  const int xslot = bid & 7;
  const int eq = xslot >> 2;                   // expert quad
  const int tg = ((bid >> 3) << 2) | (xslot & 3);
  const int row0 = tg * 64;
  const int arow = lane & 15;
  const int kch = lane >> 4;

  // ---- stage X: 64 rows x 1024 f32 -> bf16 fragment-major ---------------
#pragma unroll
  for (int i = 0; i < 16; ++i) {
    int c = i * 512 + tid;           // 64 rows x 128 chunks-of-8
    int r = c >> 7;
    int ch = c & 127;
    const float* src = x + (size_t)(row0 + r) * DIM + ch * 8;
    float4 f0 = *(const float4*)src;
    float4 f1 = *(const float4*)(src + 4);
    uint4 v;
    v.x = pk2(f0.x, f0.y); v.y = pk2(f0.z, f0.w);
    v.z = pk2(f1.x, f1.y); v.w = pk2(f1.z, f1.w);
    int f = (ch >> 2) * 4 + (r >> 4);            // ks*4 + m
    int l = ((ch & 3) << 4) | (r & 15);          // kch<<4 | row
    *(uint4*)(xs + ((size_t)(f * 64 + l)) * 8) = v;
  }
  unsigned mb[4];
#pragma unroll
  for (int m = 0; m < 4; ++m)
    mb[m] = *(const unsigned*)(msk8 + row0 + m * 16 + kch * 4);
  __syncthreads();

  const unsigned short* xp = xs + lane * 8;
  const unsigned short* hp = hs + lane * 8;

  f32x4 oacc[4][8];
#pragma unroll
  for (int m = 0; m < 4; ++m)
#pragma unroll
    for (int n = 0; n < 8; ++n) oacc[m][n] = f32x4{0.f, 0.f, 0.f, 0.f};

#pragma unroll 1
  for (int el = 0; el < 4; ++el) {
    const int e = eq * 4 + el;

#pragma unroll 1
    for (int hh = 0; hh < 2; ++hh) {
      // ---- GEMM1 pass hh: n-frags {wv+16hh, wv+8+16hh}; F=2, B unique ---
      f32x4 hacc0[4], hacc1[4];
#pragma unroll
      for (int m = 0; m < 4; ++m) {
        hacc0[m] = f32x4{0.f, 0.f, 0.f, 0.f};
        hacc1[m] = f32x4{0.f, 0.f, 0.f, 0.f};
      }
      const unsigned short* pb0 =
          w1p + ((size_t)(e * 32 + wv + 16 * hh) * 32) * 512 + lane * 8;
      const unsigned short* pb1 = pb0 + (size_t)8 * 32 * 512;
#pragma unroll 4
      for (int ks = 0; ks < 32; ++ks) {
        bf16x8 b0 = *(const bf16x8*)(pb0 + ks * 512);
        bf16x8 b1 = *(const bf16x8*)(pb1 + ks * 512);
#pragma unroll
        for (int m = 0; m < 4; ++m) {
          bf16x8 a = *(const bf16x8*)(xp + (ks * 4 + m) * 512);
          hacc0[m] = mfma_bf16(a, b0, hacc0[m]);
          hacc1[m] = mfma_bf16(a, b1, hacc1[m]);
        }
      }
      __syncthreads();   // all waves done reading hs (previous chunk/expert)

      // ---- epilogue: relu * mask-bit -> hs fragments (chunk hh) ---------
      // n'=0 -> hacc0, n'=1 -> hacc1; ks2 = (wv>>1) + 4n'
#pragma unroll
      for (int m = 0; m < 4; ++m)
#pragma unroll
        for (int j = 0; j < 4; ++j) {
          int l2 = (((wv & 1) * 2 + (arow >> 3)) << 4) | (kch * 4 + j);
          int b8 = arow & 7;
          unsigned bit = (mb[m] >> (j * 8 + e)) & 1u;
          float v0 = fmaxf(hacc0[m][j], 0.0f);
          v0 = bit ? v0 : 0.0f;
          int fr0 = ((wv >> 1) + 0) * 4 + m;
          hs[((size_t)(fr0 * 64 + l2)) * 8 + b8] = f2bf(v0);
          float v1 = fmaxf(hacc1[m][j], 0.0f);
          v1 = bit ? v1 : 0.0f;
          int fr1 = ((wv >> 1) + 4) * 4 + m;
          hs[((size_t)(fr1 * 64 + l2)) * 8 + b8] = f2bf(v1);
        }
      __syncthreads();   // hs chunk ready

      // ---- GEMM2 chunk hh: oacc[4m][8n] += hs @ W2[e][wv*8..+8, hh-half]
      const unsigned short* pc =
          w2p + ((size_t)((e * 64 + wv * 8) * 16 + hh * 8)) * 512 + lane * 8;
#pragma unroll 2
      for (int ks2 = 0; ks2 < 8; ++ks2) {
        bf16x8 a0 = *(const bf16x8*)(hp + (ks2 * 4 + 0) * 512);
        bf16x8 a1 = *(const bf16x8*)(hp + (ks2 * 4 + 1) * 512);
        bf16x8 a2 = *(const bf16x8*)(hp + (ks2 * 4 + 2) * 512);
        bf16x8 a3 = *(const bf16x8*)(hp + (ks2 * 4 + 3) * 512);
#pragma unroll
        for (int n = 0; n < 8; ++n) {
          bf16x8 b = *(const bf16x8*)(pc + (size_t)n * 8192 + ks2 * 512);
          oacc[0][n] = mfma_bf16(a0, b, oacc[0][n]);
          oacc[1][n] = mfma_bf16(a1, b, oacc[1][n]);
          oacc[2][n] = mfma_bf16(a2, b, oacc[2][n]);
          oacc[3][n] = mfma_bf16(a3, b, oacc[3][n]);
        }
      }
    }
  }

  // ---- atomic partial-sum into out (2 partials/element, commutative) -----
#pragma unroll
  for (int m = 0; m < 4; ++m)
#pragma unroll
    for (int n = 0; n < 8; ++n)
#pragma unroll
      for (int j = 0; j < 4; ++j) {
        int row = row0 + m * 16 + kch * 4 + j;
        int col = (wv * 8 + n) * 16 + arow;
        atomicAdd(&out[(size_t)row * NO + col], oacc[m][n][j]);
      }
}

extern "C" void kernel_launch(void* const* d_in, const int* in_sizes, int n_in,
                              void* d_out, int out_size, void* d_ws, size_t ws_size,
                              hipStream_t stream) {
  (void)in_sizes; (void)n_in; (void)out_size; (void)ws_size;
  const float* x  = (const float*)d_in[0];
  const float* wg = (const float*)d_in[1];
  const float* w1 = (const float*)d_in[2];
  const float* w2 = (const float*)d_in[3];
  float* out = (float*)d_out;
  char* ws = (char*)d_ws;
  unsigned short* w1p = (unsigned short*)ws;                        // 8 MB
  unsigned short* w2p = (unsigned short*)(ws + ((size_t)8 << 20));  // 8 MB
  unsigned char* msk8 = (unsigned char*)(ws + ((size_t)16 << 20));  // 8 KB

  gate_kernel<<<2048, 256, 0, stream>>>(x, wg, msk8, out);
  pack_w1_kernel<<<2048, 256, 0, stream>>>(w1, w1p);
  pack_w2_kernel<<<2048, 256, 0, stream>>>(w2, w2p);
  moe_ffn<<<256, 512, 0, stream>>>(x, w1p, w2p, msk8, out);
}

// Round 10
// 241.753 us; speedup vs baseline: 1.0310x; 1.0310x over previous
//
#include <hip/hip_runtime.h>

typedef float f32x4 __attribute__((ext_vector_type(4)));
typedef short bf16x8 __attribute__((ext_vector_type(8)));

#define NTOK 8192
#define DIM  1024
#define NE   8
#define NH   512
#define NO   1024

static __device__ __forceinline__ unsigned short f2bf(float f) {
  unsigned u = __float_as_uint(f);
  u += 0x7fffu + ((u >> 16) & 1u);
  return (unsigned short)(u >> 16);
}
static __device__ __forceinline__ unsigned pk2(float a, float b) {
  return (unsigned)f2bf(a) | ((unsigned)f2bf(b) << 16);
}

static __device__ __forceinline__ f32x4 mfma_bf16(bf16x8 a, bf16x8 b, f32x4 c) {
  return __builtin_amdgcn_mfma_f32_16x16x32_bf16(a, b, c, 0, 0, 0);
}

// ---------------------------------------------------------------------------
// Gate: fp64 logits -> top-4 bitmask byte per token. Also zeroes d_out
// (16 floats/thread) so moe_expert can atomicAdd partials.
// ---------------------------------------------------------------------------
__global__ __launch_bounds__(256) void gate_kernel(
    const float* __restrict__ x, const float* __restrict__ wg,
    unsigned char* __restrict__ msk8, float* __restrict__ out)
{
  {
    size_t t = (size_t)blockIdx.x * 256 + threadIdx.x;
    float4* op = (float4*)(out + t * 16);
    float4 z4 = {0.f, 0.f, 0.f, 0.f};
    op[0] = z4; op[1] = z4; op[2] = z4; op[3] = z4;
  }
  const int lane = threadIdx.x & 63;
  const int wv = threadIdx.x >> 6;
  const int n = blockIdx.x * 4 + wv;
  const float* xr = x + (size_t)n * DIM;
  float4 v[4];
#pragma unroll
  for (int i = 0; i < 4; ++i) v[i] = *(const float4*)(xr + i * 256 + lane * 4);
  double logit[NE];
#pragma unroll
  for (int e = 0; e < NE; ++e) {
    const float* wr = wg + e * DIM;
    double s = 0.0;
#pragma unroll
    for (int i = 0; i < 4; ++i) {
      float4 g = *(const float4*)(wr + i * 256 + lane * 4);
      s += (double)v[i].x * g.x + (double)v[i].y * g.y +
           (double)v[i].z * g.z + (double)v[i].w * g.w;
    }
#pragma unroll
    for (int off = 32; off; off >>= 1) s += __shfl_down(s, off);
    logit[e] = s;
  }
  if (lane == 0) {
    unsigned sel = 0;
#pragma unroll
    for (int t = 0; t < 4; ++t) {
      int best = 0; double bv = -1.0e300;
#pragma unroll
      for (int e = 0; e < NE; ++e)
        if (!((sel >> e) & 1) && logit[e] > bv) { bv = logit[e]; best = e; }
      sel |= 1u << best;
    }
    msk8[n] = (unsigned char)sel;
  }
}

// ---------------------------------------------------------------------------
// Deterministic per-expert token lists (sorted by token id) + counts.
// One block per expert, block-wide prefix scan, no atomics.
// ---------------------------------------------------------------------------
__global__ __launch_bounds__(1024) void build_lists(
    const unsigned char* __restrict__ msk8, int* __restrict__ lst,
    int* __restrict__ cnt)
{
  __shared__ int wsum[16];
  __shared__ int wpref[16];
  __shared__ int base_s;
  const int e = blockIdx.x;
  const int tid = threadIdx.x;
  const int lane = tid & 63, wv = tid >> 6;
  if (tid == 0) base_s = 0;
  __syncthreads();
#pragma unroll 1
  for (int c = 0; c < NTOK; c += 1024) {
    int tok = c + tid;
    int flag = (msk8[tok] >> e) & 1;
    unsigned long long ball = __ballot(flag);
    int lpref = __popcll(ball & ((1ull << lane) - 1ull));
    int tot = __popcll(ball);
    if (lane == 0) wsum[wv] = tot;
    __syncthreads();
    if (wv == 0 && lane < 16) {
      int p = 0;
      for (int k = 0; k < lane; ++k) p += wsum[k];
      wpref[lane] = p;
    }
    __syncthreads();
    int pos = base_s + wpref[wv] + lpref;
    if (flag) lst[e * NTOK + pos] = tok;
    __syncthreads();
    if (tid == 0) {
      int t = 0;
      for (int k = 0; k < 16; ++k) t += wsum[k];
      base_s += t;
    }
    __syncthreads();
  }
  if (tid == 0) cnt[e] = base_s;
}

// ---------------------------------------------------------------------------
// Weight packs (unchanged): fragment-major bf16.
// w1p [e][nt:32][ks:32][lane:64][j:8]; elem = w1[e][nt*16+(l&15)][ks*32+(l>>4)*8+j]
// w2p [e][ot:64][ks2:16][lane:64][j:8]; elem = w2[e][ot*16+(l&15)][ks2*32+(l>>4)*8+j]
// ---------------------------------------------------------------------------
__global__ __launch_bounds__(256) void pack_w1_kernel(
    const float* __restrict__ w1, unsigned short* __restrict__ w1p)
{
  int t = blockIdx.x * 256 + threadIdx.x;
  int lane = t & 63, ks = (t >> 6) & 31, nt = (t >> 11) & 31, e = t >> 16;
  int r = nt * 16 + (lane & 15);
  int c = ks * 32 + (lane >> 4) * 8;
  const float* src = w1 + ((size_t)(e * 512 + r)) * 1024 + c;
  float4 f0 = *(const float4*)src;
  float4 f1 = *(const float4*)(src + 4);
  uint4 v;
  v.x = pk2(f0.x, f0.y); v.y = pk2(f0.z, f0.w);
  v.z = pk2(f1.x, f1.y); v.w = pk2(f1.z, f1.w);
  *(uint4*)(w1p + (size_t)t * 8) = v;
}

__global__ __launch_bounds__(256) void pack_w2_kernel(
    const float* __restrict__ w2, unsigned short* __restrict__ w2p)
{
  int t = blockIdx.x * 256 + threadIdx.x;
  int lane = t & 63, ks = (t >> 6) & 15, ot = (t >> 10) & 63, e = t >> 16;
  int o = ot * 16 + (lane & 15);
  int h = ks * 32 + (lane >> 4) * 8;
  const float* src = w2 + ((size_t)(e * 1024 + o)) * 512 + h;
  float4 f0 = *(const float4*)src;
  float4 f1 = *(const float4*)(src + 4);
  uint4 v;
  v.x = pk2(f0.x, f0.y); v.y = pk2(f0.z, f0.w);
  v.z = pk2(f1.x, f1.y); v.w = pk2(f1.z, f1.w);
  *(uint4*)(w2p + (size_t)t * 8) = v;
}

// ---------------------------------------------------------------------------
// Expert-grouped MoE FFN, round 10: block = (expert e, tile of 64 gathered
// tokens). Top-4 sparsity exploited: only selected (token,expert) pairs are
// computed -> half the MFMA/LDS/weight work of the dense kernels.
//   e = bid & 7  -> all blocks of expert e land on XCD e (weights L2-hot)
//   G1: wave owns H-frags {wv, wv+16} (F=2, B unique); hacc0/hacc1 named.
//   per H-chunk hh: epi (relu only — mask always 1 for gathered tokens,
//   pad rows are zero by construction) -> hs -> G2 (wave owns 4 O-frags).
// Partials (4 per out element, one per selected expert) via atomicAdd.
// xs 128 KB + hs 32 KB = 160 KB. 16 waves. R8-verified fragment mappings.
// ---------------------------------------------------------------------------
__global__ __launch_bounds__(1024, 4) void moe_expert(
    const float* __restrict__ x, const unsigned short* __restrict__ w1p,
    const unsigned short* __restrict__ w2p, const int* __restrict__ lst,
    const int* __restrict__ cnt, float* __restrict__ out)
{
  __shared__ unsigned short xs[128 * 64 * 8];  // 128 KB: frag f = ks*4+m
  __shared__ unsigned short hs[32 * 64 * 8];   // 32 KB: frag fr = ks2*4+m

  const int e = blockIdx.x & 7;
  const int tile = blockIdx.x >> 3;
  const int nct = cnt[e];
  if (tile * 64 >= nct) return;                // empty tail block
  const int row0 = tile * 64;

  const int tid = threadIdx.x;
  const int lane = tid & 63;
  const int wv = tid >> 6;
  const int arow = lane & 15;
  const int kch = lane >> 4;
  const int* mylst = lst + e * NTOK;

  // ---- stage gathered X rows: 64 x 1024 f32 -> bf16 fragment-major ------
#pragma unroll
  for (int i = 0; i < 8; ++i) {
    int c = i * 1024 + tid;          // 64 rows x 128 chunks-of-8
    int r = c >> 7;
    int ch = c & 127;
    uint4 v;
    if (row0 + r < nct) {
      int tok = mylst[row0 + r];
      const float* src = x + (size_t)tok * DIM + ch * 8;
      float4 f0 = *(const float4*)src;
      float4 f1 = *(const float4*)(src + 4);
      v.x = pk2(f0.x, f0.y); v.y = pk2(f0.z, f0.w);
      v.z = pk2(f1.x, f1.y); v.w = pk2(f1.z, f1.w);
    } else {
      v = uint4{0u, 0u, 0u, 0u};     // pad row -> zero -> zero contribution
    }
    int f = (ch >> 2) * 4 + (r >> 4);            // ks*4 + m
    int l = ((ch & 3) << 4) | (r & 15);          // kch<<4 | row
    *(uint4*)(xs + ((size_t)(f * 64 + l)) * 8) = v;
  }
  __syncthreads();

  const unsigned short* xp = xs + lane * 8;
  const unsigned short* hp = hs + lane * 8;

  f32x4 oacc[4][4];
#pragma unroll
  for (int m = 0; m < 4; ++m)
#pragma unroll
    for (int n = 0; n < 4; ++n) oacc[m][n] = f32x4{0.f, 0.f, 0.f, 0.f};

  // ---- GEMM1: full H; wave = 4m x {wv, wv+16}; B unique ------------------
  f32x4 hacc0[4], hacc1[4];
#pragma unroll
  for (int m = 0; m < 4; ++m) {
    hacc0[m] = f32x4{0.f, 0.f, 0.f, 0.f};
    hacc1[m] = f32x4{0.f, 0.f, 0.f, 0.f};
  }
  {
    const unsigned short* pb0 = w1p + ((size_t)(e * 32 + wv) * 32) * 512 + lane * 8;
    const unsigned short* pb1 = pb0 + (size_t)16 * 32 * 512;
#pragma unroll 4
    for (int ks = 0; ks < 32; ++ks) {
      bf16x8 b0 = *(const bf16x8*)(pb0 + ks * 512);
      bf16x8 b1 = *(const bf16x8*)(pb1 + ks * 512);
#pragma unroll
      for (int m = 0; m < 4; ++m) {
        bf16x8 a = *(const bf16x8*)(xp + (ks * 4 + m) * 512);
        hacc0[m] = mfma_bf16(a, b0, hacc0[m]);
        hacc1[m] = mfma_bf16(a, b1, hacc1[m]);
      }
    }
  }

  // ---- two H-chunks: epilogue -> hs -> GEMM2 (hh fully unrolled) ---------
#pragma unroll
  for (int hh = 0; hh < 2; ++hh) {
    __syncthreads();   // previous chunk's GEMM2 done reading hs

    // epilogue: relu -> hs fragments (mask always 1 for gathered tokens)
#pragma unroll
    for (int m = 0; m < 4; ++m)
#pragma unroll
      for (int j = 0; j < 4; ++j) {
        float hv = hh ? hacc1[m][j] : hacc0[m][j];   // static after unroll
        float v = fmaxf(hv, 0.0f);
        int fr = (wv >> 1) * 4 + m;
        int l2 = (((wv & 1) * 2 + (arow >> 3)) << 4) | (kch * 4 + j);
        hs[((size_t)(fr * 64 + l2)) * 8 + (arow & 7)] = f2bf(v);
      }
    __syncthreads();   // hs chunk ready

    // GEMM2 chunk: oacc[4m][4n] += hs_chunk @ W2[e][wv*4..+4, hh-half]
    const unsigned short* pc =
        w2p + ((size_t)((e * 64 + wv * 4) * 16 + hh * 8)) * 512 + lane * 8;
#pragma unroll 2
    for (int ks2 = 0; ks2 < 8; ++ks2) {
      bf16x8 a0 = *(const bf16x8*)(hp + (ks2 * 4 + 0) * 512);
      bf16x8 a1 = *(const bf16x8*)(hp + (ks2 * 4 + 1) * 512);
      bf16x8 a2 = *(const bf16x8*)(hp + (ks2 * 4 + 2) * 512);
      bf16x8 a3 = *(const bf16x8*)(hp + (ks2 * 4 + 3) * 512);
#pragma unroll
      for (int n = 0; n < 4; ++n) {
        bf16x8 b = *(const bf16x8*)(pc + (size_t)n * 8192 + ks2 * 512);
        oacc[0][n] = mfma_bf16(a0, b, oacc[0][n]);
        oacc[1][n] = mfma_bf16(a1, b, oacc[1][n]);
        oacc[2][n] = mfma_bf16(a2, b, oacc[2][n]);
        oacc[3][n] = mfma_bf16(a3, b, oacc[3][n]);
      }
    }
  }

  // ---- scatter partial sums (skip pad rows) ------------------------------
#pragma unroll
  for (int m = 0; m < 4; ++m)
#pragma unroll
    for (int j = 0; j < 4; ++j) {
      int g = row0 + m * 16 + kch * 4 + j;
      if (g < nct) {
        int tok = mylst[g];
#pragma unroll
        for (int n = 0; n < 4; ++n) {
          int col = (wv * 4 + n) * 16 + arow;
          atomicAdd(&out[(size_t)tok * NO + col], oacc[m][n][j]);
        }
      }
    }
}

extern "C" void kernel_launch(void* const* d_in, const int* in_sizes, int n_in,
                              void* d_out, int out_size, void* d_ws, size_t ws_size,
                              hipStream_t stream) {
  (void)in_sizes; (void)n_in; (void)out_size; (void)ws_size;
  const float* x  = (const float*)d_in[0];
  const float* wg = (const float*)d_in[1];
  const float* w1 = (const float*)d_in[2];
  const float* w2 = (const float*)d_in[3];
  float* out = (float*)d_out;
  char* ws = (char*)d_ws;
  unsigned short* w1p = (unsigned short*)ws;                        // 8 MB
  unsigned short* w2p = (unsigned short*)(ws + ((size_t)8 << 20));  // 8 MB
  unsigned char* msk8 = (unsigned char*)(ws + ((size_t)16 << 20));  // 8 KB
  int* lst = (int*)(ws + ((size_t)16 << 20) + 8192);                // 256 KB
  int* cnt = (int*)(ws + ((size_t)16 << 20) + 8192 + NE * NTOK * 4);// 32 B

  gate_kernel<<<2048, 256, 0, stream>>>(x, wg, msk8, out);
  build_lists<<<NE, 1024, 0, stream>>>(msk8, lst, cnt);
  pack_w1_kernel<<<2048, 256, 0, stream>>>(w1, w1p);
  pack_w2_kernel<<<2048, 256, 0, stream>>>(w2, w2p);
  moe_expert<<<NE * 128, 1024, 0, stream>>>(x, w1p, w2p, lst, cnt, out);
}